// Round 10
// baseline (3773.167 us; speedup 1.0000x reference)
//
#include <hip/hip_runtime.h>
#include <math.h>

// Problem dims (fixed by reference)
#define BB 32
#define CC 8
#define TT 64
#define FF 256
#define HH 512
#define G3 1536
#define NSEQ 256            // BB*CC
#define MROWS 16384         // NSEQ*TT

#define SGRP 16             // sequence groups (16 seqs each)
#define NG2 16              // N-split ways (96 preact cols = 32 h-cols each)

typedef _Float16 f16x8 __attribute__((ext_vector_type(8)));
typedef float f32x4 __attribute__((ext_vector_type(4)));

// ---------------- input GEMM: C[M][N] = A[M][K] @ W[N][K]^T + bias[N] ----------------
#define TMg 128
#define TNg 128
#define TKg 16

__global__ __launch_bounds__(256) void gemm_bias(
    const float* __restrict__ A, const float* __restrict__ W,
    const float* __restrict__ bias, float* __restrict__ C,
    int M, int N, int K)
{
  __shared__ float As[TKg][TMg + 4];
  __shared__ float Ws[TKg][TNg + 4];
  const int bm = blockIdx.y * TMg;
  const int bn = blockIdx.x * TNg;
  const int tid = threadIdx.x;
  const int tx = tid & 15;
  const int ty = tid >> 4;
  float acc[8][8];
#pragma unroll
  for (int i = 0; i < 8; ++i)
#pragma unroll
    for (int j = 0; j < 8; ++j) acc[i][j] = 0.f;

  for (int k0 = 0; k0 < K; k0 += TKg) {
    __syncthreads();
#pragma unroll
    for (int i = 0; i < 8; ++i) {
      int e = i * 256 + tid;
      int r = e >> 4;
      int c = e & 15;
      As[c][r] = A[(size_t)(bm + r) * K + (k0 + c)];
      Ws[c][r] = W[(size_t)(bn + r) * K + (k0 + c)];
    }
    __syncthreads();
#pragma unroll
    for (int k = 0; k < TKg; ++k) {
      float a[8], w[8];
#pragma unroll
      for (int i = 0; i < 8; ++i) a[i] = As[k][ty * 8 + i];
#pragma unroll
      for (int j = 0; j < 8; ++j) w[j] = Ws[k][tx + 16 * j];
#pragma unroll
      for (int i = 0; i < 8; ++i)
#pragma unroll
        for (int j = 0; j < 8; ++j) acc[i][j] = fmaf(a[i], w[j], acc[i][j]);
    }
  }
#pragma unroll
  for (int i = 0; i < 8; ++i) {
    size_t m = (size_t)(bm + ty * 8 + i);
#pragma unroll
    for (int j = 0; j < 8; ++j) {
      int n = bn + tx + 16 * j;
      C[m * N + n] = acc[i][j] + bias[n];
    }
  }
}

// ---------------- pack Whh[G3][HH] fp32 -> fp16 B-fragments, 16-way N-split order ------
// P[ng(16)][tl(6)][kc(16)][lane(64)][8]; tl = gate*2 + sub; global tile gt = gate*32 + ng*2 + sub
// B-frag (16x16x32_f16): n = lane&15 (Whh row within tile), k = kc*32 + (lane>>4)*8 + i
__global__ __launch_bounds__(256) void pack_whh(
    const float* __restrict__ W, _Float16* __restrict__ P)
{
  int id = blockIdx.x * 256 + threadIdx.x;    // 0 .. 98303
  int lane = id & 63;
  int kc = (id >> 6) & 15;
  int tidx = id >> 10;                        // 0..95 = ng*6 + tl
  int ng = tidx / 6;
  int tl = tidx % 6;
  int g = tl >> 1, sub = tl & 1;
  int gt = g * 32 + ng * 2 + sub;             // global 16-row tile of Whh
  int row = gt * 16 + (lane & 15);
  int k0 = kc * 32 + ((lane >> 4) * 8);
  const float* src = W + (size_t)row * HH + k0;
  f16x8 v;
#pragma unroll
  for (int i = 0; i < 8; ++i) v[i] = (_Float16)src[i];
  *reinterpret_cast<f16x8*>(P + (size_t)id * 8) = v;
}

// ---------------- MFMA recurrent scan: weights LDS-persistent, 256 blocks ----------------
// 256 blocks = 16 seq-groups x 16 N-groups, 128 threads (2 waves). Each block preloads
// its 96 KB weight slice into LDS ONCE (zero per-step weight traffic). Wave wv owns one
// 16-col group x 3 gates. h exchange via hx global (fp16, double-buffered); A-fragments
// read directly from hx (acquire-inv covers CU L1 / XCD L2 — mechanism validated r7/r8).
// Sync: per-block release-store flag + 16 parallel poller lanes (no RMW chain).
// Launched cooperatively (residency guarantee for 256 blocks; proven w/ graphs in r0).
#define SPB2 16

__device__ __forceinline__ void gload16(const _Float16* g, _Float16* l) {
  __builtin_amdgcn_global_load_lds(
      (const __attribute__((address_space(1))) unsigned int*)g,
      (__attribute__((address_space(3))) unsigned int*)l, 16, 0, 0);
}

__global__ __launch_bounds__(128, 2) void gru_scan_mfma(
    const float* __restrict__ gi,      // [NSEQ][TT][G3]
    const _Float16* __restrict__ packW,
    const float* __restrict__ bhh,     // [G3]
    float* __restrict__ hfin,          // [NSEQ][HH]
    float* __restrict__ yout,          // [NSEQ][TT][HH] or nullptr
    _Float16* __restrict__ hx,         // [2][NSEQ][HH] exchange (buf0 zeroed pre-launch)
    unsigned int* __restrict__ flags)  // [SGRP][NG2][TT], zeroed pre-launch
{
  __shared__ __align__(16) _Float16 wlds[6 * 16 * 64 * 8];   // 96 KB

  const int tid = threadIdx.x;
  const int lane = tid & 63;
  const int wv = tid >> 6;                    // 0..1
  const int bid = blockIdx.x;
  const int sg = bid >> 4;                    // seq group
  const int ng = bid & 15;                    // N group
  const int seq0 = sg * SPB2;

  const int arow = lane & 15;                 // A-frag row (seq)
  const int agrp = lane >> 4;
  const int dcol = lane & 15;                 // D-frag col within tile
  const int mrow = (lane >> 4) * 4;           // D-frag first row (seq)

  const int cg = (ng * 2 + wv) * 16 + dcol;   // this lane's h column (global)

  // ---- preload this block's 96 KB weight slice into LDS (one-time) ----
  {
    const _Float16* slice = packW + (size_t)ng * (6 * 16 * 64 * 8);
#pragma unroll 4
    for (int it = 0; it < 48; ++it) {
      const _Float16* src = slice + (size_t)(it * 128 + tid) * 8;  // per-lane global
      _Float16* dst = &wlds[(size_t)(it * 128 + wv * 64) * 8];     // wave-uniform base
      gload16(src, dst);
    }
  }

  const float bhr = bhh[cg];
  const float bhz = bhh[HH + cg];
  const float bhn = bhh[2 * HH + cg];

  float hold[4] = {0.f, 0.f, 0.f, 0.f};

  __syncthreads();   // weight staging complete (drains vmcnt)

  const int tR = wv, tZ = 2 + wv, tN = 4 + wv;

  for (int t = 0; t < TT; ++t) {
    const int cb = t & 1;
    const int nb = cb ^ 1;

    // ---- gi loads: independent of hx -> issue BEFORE the flag wait ----
    float gir[4], giz[4], gin[4];
#pragma unroll
    for (int r = 0; r < 4; ++r) {
      const float* p0 = gi + ((size_t)(seq0 + mrow + r) * TT + t) * G3;
      gir[r] = p0[cg];
      giz[r] = p0[HH + cg];
      gin[r] = p0[2 * HH + cg];
    }

    if (t > 0) {
      // 16 poller lanes, one per producer block of this group (own cacheline rows)
      if (tid < NG2) {
        while (__hip_atomic_load(&flags[(sg * NG2 + tid) * TT + (t - 1)],
                                 __ATOMIC_ACQUIRE, __HIP_MEMORY_SCOPE_AGENT) == 0u) {}
      }
      __syncthreads();
    }

    // ---- A fragments straight from hx[cb] (LLC; acquire-inv'd above) ----
    const _Float16* hrow = hx + (size_t)cb * NSEQ * HH
                           + (size_t)(seq0 + arow) * HH + agrp * 8;
    f16x8 af[16];
#pragma unroll
    for (int kc = 0; kc < 16; ++kc)
      af[kc] = *reinterpret_cast<const f16x8*>(hrow + kc * 32);

    // ---- 3 gate tiles from LDS-persistent weights ----
    f32x4 aR = {0.f,0.f,0.f,0.f}, aZ = {0.f,0.f,0.f,0.f}, aN = {0.f,0.f,0.f,0.f};
#pragma unroll
    for (int kc = 0; kc < 16; ++kc) {
      f16x8 br = *reinterpret_cast<const f16x8*>(&wlds[(size_t)((tR * 16 + kc) * 64 + lane) * 8]);
      f16x8 bz = *reinterpret_cast<const f16x8*>(&wlds[(size_t)((tZ * 16 + kc) * 64 + lane) * 8]);
      f16x8 bn = *reinterpret_cast<const f16x8*>(&wlds[(size_t)((tN * 16 + kc) * 64 + lane) * 8]);
      aR = __builtin_amdgcn_mfma_f32_16x16x32_f16(af[kc], br, aR, 0, 0, 0);
      aZ = __builtin_amdgcn_mfma_f32_16x16x32_f16(af[kc], bz, aZ, 0, 0, 0);
      aN = __builtin_amdgcn_mfma_f32_16x16x32_f16(af[kc], bn, aN, 0, 0, 0);
    }

    // ---- register-local gate epilogue: 4 seqs x 1 col per lane ----
#pragma unroll
    for (int r = 0; r < 4; ++r) {
      float hr = aR[r] + bhr;
      float hz = aZ[r] + bhz;
      float hn = aN[r] + bhn;
      float rr = __builtin_amdgcn_rcpf(1.f + __expf(-(gir[r] + hr)));
      float zz = __builtin_amdgcn_rcpf(1.f + __expf(-(giz[r] + hz)));
      float ex = __expf(2.f * (gin[r] + rr * hn));
      float nn = 1.f - 2.f * __builtin_amdgcn_rcpf(ex + 1.f);
      float hnew = nn + zz * (hold[r] - nn);
      hold[r] = hnew;
      hx[(size_t)nb * NSEQ * HH + (size_t)(seq0 + mrow + r) * HH + cg] = (_Float16)hnew;
      if (yout)
        yout[((size_t)(seq0 + mrow + r) * TT + t) * HH + cg] = hnew;
    }

    // publish step t: own stores visible, then release-store own flag
    __threadfence();
    __syncthreads();
    if (tid == 0)
      __hip_atomic_store(&flags[(sg * NG2 + ng) * TT + t], 1u,
                         __ATOMIC_RELEASE, __HIP_MEMORY_SCOPE_AGENT);
  }

#pragma unroll
  for (int r = 0; r < 4; ++r)
    hfin[(size_t)(seq0 + mrow + r) * HH + cg] = hold[r];
}

// ---------------- fallback fp32 scan (row-streaming) ----------------
#define QS 4
#define SCTH 512
__global__ __launch_bounds__(SCTH) void gru_scan2f(
    const float* __restrict__ gi, const float* __restrict__ W,
    const float* __restrict__ bhh, float* __restrict__ hfin,
    float* __restrict__ yout)
{
  __shared__ __align__(16) float hsl[HH][QS];
  const int col = threadIdx.x;
  const int seq0 = blockIdx.x * QS;
  const float bh0 = bhh[col];
  const float bh1 = bhh[HH + col];
  const float bh2 = bhh[2 * HH + col];
  const float* w0p = W + (size_t)col * HH;
  const float* w1p = W + (size_t)(HH + col) * HH;
  const float* w2p = W + (size_t)(2 * HH + col) * HH;

  *reinterpret_cast<float4*>(&hsl[col][0]) = make_float4(0.f, 0.f, 0.f, 0.f);
  __syncthreads();

  for (int t = 0; t < TT; ++t) {
    float acc0[QS], acc1[QS], acc2[QS];
#pragma unroll
    for (int s = 0; s < QS; ++s) { acc0[s] = bh0; acc1[s] = bh1; acc2[s] = bh2; }
    float4 ho = *reinterpret_cast<const float4*>(&hsl[col][0]);
    float hold[QS] = {ho.x, ho.y, ho.z, ho.w};
#pragma unroll 2
    for (int k0 = 0; k0 < HH; k0 += 4) {
      float w[3][4];
      float4 a = *reinterpret_cast<const float4*>(&w0p[k0]);
      w[0][0] = a.x; w[0][1] = a.y; w[0][2] = a.z; w[0][3] = a.w;
      float4 b = *reinterpret_cast<const float4*>(&w1p[k0]);
      w[1][0] = b.x; w[1][1] = b.y; w[1][2] = b.z; w[1][3] = b.w;
      float4 c = *reinterpret_cast<const float4*>(&w2p[k0]);
      w[2][0] = c.x; w[2][1] = c.y; w[2][2] = c.z; w[2][3] = c.w;
#pragma unroll
      for (int kk = 0; kk < 4; ++kk) {
        float4 h4 = *reinterpret_cast<const float4*>(&hsl[k0 + kk][0]);
        float hq[4] = {h4.x, h4.y, h4.z, h4.w};
#pragma unroll
        for (int s = 0; s < QS; ++s) {
          acc0[s] = fmaf(hq[s], w[0][kk], acc0[s]);
          acc1[s] = fmaf(hq[s], w[1][kk], acc1[s]);
          acc2[s] = fmaf(hq[s], w[2][kk], acc2[s]);
        }
      }
    }
    __syncthreads();
    float hnew[QS];
#pragma unroll
    for (int s = 0; s < QS; ++s) {
      size_t grow = ((size_t)(seq0 + s) * TT + t) * G3;
      float ir = gi[grow + col];
      float iz = gi[grow + HH + col];
      float inn = gi[grow + 2 * HH + col];
      float r = 1.f / (1.f + expf(-(ir + acc0[s])));
      float z = 1.f / (1.f + expf(-(iz + acc1[s])));
      float nn = tanhf(inn + r * acc2[s]);
      hnew[s] = (1.f - z) * nn + z * hold[s];
      if (yout) yout[((size_t)(seq0 + s) * TT + t) * HH + col] = hnew[s];
    }
    *reinterpret_cast<float4*>(&hsl[col][0]) =
        make_float4(hnew[0], hnew[1], hnew[2], hnew[3]);
    __syncthreads();
  }
#pragma unroll
  for (int s = 0; s < QS; ++s)
    hfin[(size_t)(seq0 + s) * HH + col] = hsl[col][s];
}

// ---------------- final FC + channel mean ----------------
__global__ __launch_bounds__(256) void fc_mean(
    const float* __restrict__ hfin, const float* __restrict__ fcW,
    const float* __restrict__ fcb, float* __restrict__ out)
{
  __shared__ float red[256];
  const int b = blockIdx.x;
  const int tid = threadIdx.x;
  float sum = 0.f;
  for (int e = tid; e < CC * HH; e += 256) {
    int c = e >> 9;
    int k = e & (HH - 1);
    sum += hfin[(size_t)(b * CC + c) * HH + k] * fcW[k];
  }
  red[tid] = sum;
  __syncthreads();
  for (int w = 128; w > 0; w >>= 1) {
    if (tid < w) red[tid] += red[tid + w];
    __syncthreads();
  }
  if (tid == 0) out[b] = red[0] * (1.f / CC) + fcb[0];
}

extern "C" void kernel_launch(void* const* d_in, const int* in_sizes, int n_in,
                              void* d_out, int out_size, void* d_ws, size_t ws_size,
                              hipStream_t stream)
{
  const float* x    = (const float*)d_in[0];
  const float* Wih0 = (const float*)d_in[1];
  const float* Whh0 = (const float*)d_in[2];
  const float* bih0 = (const float*)d_in[3];
  const float* bhh0 = (const float*)d_in[4];
  const float* Wih1 = (const float*)d_in[5];
  const float* Whh1 = (const float*)d_in[6];
  const float* bih1 = (const float*)d_in[7];
  const float* bhh1 = (const float*)d_in[8];
  const float* fcW  = (const float*)d_in[9];
  const float* fcb  = (const float*)d_in[10];
  float* out = (float*)d_out;

  // ws layout:
  //   gi   [MROWS][G3] fp32   100,663,296 @ 0
  //   y0   [MROWS][HH] fp32    33,554,432 @ 100,663,296
  //   hfin [NSEQ][HH]  fp32       524,288 @ 134,217,728
  //   pack fp16               1,572,864 @ 134,742,016
  //   hx   [2][NSEQ][HH] fp16   524,288 @ 136,314,880
  //   flags [SGRP][NG2][TT] u32  65,536 @ 136,839,168   (end 136,904,704)
  // ws_size >= 137,887,744 proven in round 2/3 (that gate passed and MFMA ran).
  char* ws = (char*)d_ws;
  float* gibuf = (float*)ws;
  float* y0    = (float*)(ws + 100663296ull);
  float* hfin  = (float*)(ws + 134217728ull);
  _Float16* packb = (_Float16*)(ws + 134742016ull);
  _Float16* hx    = (_Float16*)(ws + 136314880ull);
  unsigned int* flags = (unsigned int*)(ws + 136839168ull);
  const bool mfma_ok = (ws_size >= 136904704ull);

  // layer 0 input GEMM
  gemm_bias<<<dim3(G3 / TNg, MROWS / TMg), 256, 0, stream>>>(x, Wih0, bih0, gibuf, MROWS, G3, FF);

  if (mfma_ok) {
    pack_whh<<<dim3(384), 256, 0, stream>>>(Whh0, packb);
    hipMemsetAsync(flags, 0, SGRP * NG2 * TT * sizeof(unsigned int), stream);
    hipMemsetAsync(hx, 0, (size_t)NSEQ * HH * sizeof(_Float16), stream);  // buffer 0 = h(t=0)
    {
      const float* giarg = gibuf; const _Float16* pwarg = packb; const float* bharg = bhh0;
      float* hfarg = hfin; float* yarg = y0; _Float16* hxarg = hx; unsigned int* flarg = flags;
      void* args[] = {(void*)&giarg, (void*)&pwarg, (void*)&bharg, (void*)&hfarg,
                      (void*)&yarg, (void*)&hxarg, (void*)&flarg};
      hipLaunchCooperativeKernel((const void*)gru_scan_mfma, dim3(SGRP * NG2), dim3(128),
                                 args, 0, stream);
    }
  } else {
    gru_scan2f<<<dim3(NSEQ / QS), SCTH, 0, stream>>>(gibuf, Whh0, bhh0, hfin, y0);
  }

  // layer 1 input GEMM (gi reused)
  gemm_bias<<<dim3(G3 / TNg, MROWS / TMg), 256, 0, stream>>>(y0, Wih1, bih1, gibuf, MROWS, G3, HH);

  if (mfma_ok) {
    pack_whh<<<dim3(384), 256, 0, stream>>>(Whh1, packb);
    hipMemsetAsync(flags, 0, SGRP * NG2 * TT * sizeof(unsigned int), stream);
    hipMemsetAsync(hx, 0, (size_t)NSEQ * HH * sizeof(_Float16), stream);
    {
      const float* giarg = gibuf; const _Float16* pwarg = packb; const float* bharg = bhh1;
      float* hfarg = hfin; float* yarg = nullptr; _Float16* hxarg = hx; unsigned int* flarg = flags;
      void* args[] = {(void*)&giarg, (void*)&pwarg, (void*)&bharg, (void*)&hfarg,
                      (void*)&yarg, (void*)&hxarg, (void*)&flarg};
      hipLaunchCooperativeKernel((const void*)gru_scan_mfma, dim3(SGRP * NG2), dim3(128),
                                 args, 0, stream);
    }
  } else {
    gru_scan2f<<<dim3(NSEQ / QS), SCTH, 0, stream>>>(gibuf, Whh1, bhh1, hfin, nullptr);
  }

  fc_mean<<<dim3(BB), 256, 0, stream>>>(hfin, fcW, fcb, out);
}

// Round 12
// 2741.876 us; speedup vs baseline: 1.3761x; 1.3761x over previous
//
#include <hip/hip_runtime.h>
#include <math.h>

// Problem dims (fixed by reference)
#define BB 32
#define CC 8
#define TT 64
#define FF 256
#define HH 512
#define G3 1536
#define NSEQ 256            // BB*CC
#define MROWS 16384         // NSEQ*TT

#define SGRP 16             // sequence groups (16 seqs each)
#define NGRP 4              // N-split ways (384 preact cols each)

typedef _Float16 f16x8 __attribute__((ext_vector_type(8)));
typedef float f32x4 __attribute__((ext_vector_type(4)));

// ---------------- input GEMM: C[M][N] = A[M][K] @ W[N][K]^T + bias[N] ----------------
#define TMg 128
#define TNg 128
#define TKg 16

__global__ __launch_bounds__(256) void gemm_bias(
    const float* __restrict__ A, const float* __restrict__ W,
    const float* __restrict__ bias, float* __restrict__ C,
    int M, int N, int K)
{
  __shared__ float As[TKg][TMg + 4];
  __shared__ float Ws[TKg][TNg + 4];
  const int bm = blockIdx.y * TMg;
  const int bn = blockIdx.x * TNg;
  const int tid = threadIdx.x;
  const int tx = tid & 15;
  const int ty = tid >> 4;
  float acc[8][8];
#pragma unroll
  for (int i = 0; i < 8; ++i)
#pragma unroll
    for (int j = 0; j < 8; ++j) acc[i][j] = 0.f;

  for (int k0 = 0; k0 < K; k0 += TKg) {
    __syncthreads();
#pragma unroll
    for (int i = 0; i < 8; ++i) {
      int e = i * 256 + tid;
      int r = e >> 4;
      int c = e & 15;
      As[c][r] = A[(size_t)(bm + r) * K + (k0 + c)];
      Ws[c][r] = W[(size_t)(bn + r) * K + (k0 + c)];
    }
    __syncthreads();
#pragma unroll
    for (int k = 0; k < TKg; ++k) {
      float a[8], w[8];
#pragma unroll
      for (int i = 0; i < 8; ++i) a[i] = As[k][ty * 8 + i];
#pragma unroll
      for (int j = 0; j < 8; ++j) w[j] = Ws[k][tx + 16 * j];
#pragma unroll
      for (int i = 0; i < 8; ++i)
#pragma unroll
        for (int j = 0; j < 8; ++j) acc[i][j] = fmaf(a[i], w[j], acc[i][j]);
    }
  }
#pragma unroll
  for (int i = 0; i < 8; ++i) {
    size_t m = (size_t)(bm + ty * 8 + i);
#pragma unroll
    for (int j = 0; j < 8; ++j) {
      int n = bn + tx + 16 * j;
      C[m * N + n] = acc[i][j] + bias[n];
    }
  }
}

// ---------------- pack Whh[G3][HH] fp32 -> fp16 B-fragments, 4-way N-split order ------
// P[ng(4)][tl(24)][kc(16)][lane(64)][8]; tl = gate*8 + sub; global tile = gate*32+ng*8+sub
// B-frag (16x16x32_f16): n = lane&15 (Whh row within tile), k = kc*32 + (lane>>4)*8 + i
__global__ __launch_bounds__(256) void pack_whh(
    const float* __restrict__ W, _Float16* __restrict__ P)
{
  int id = blockIdx.x * 256 + threadIdx.x;    // 0 .. 98303
  int lane = id & 63;
  int kc = (id >> 6) & 15;
  int tidx = id >> 10;                        // 0..95 = ng*24 + tl
  int ng = tidx / 24;
  int tl = tidx % 24;
  int g = tl >> 3, sub = tl & 7;
  int gt = g * 32 + ng * 8 + sub;             // global 16-row tile of Whh
  int row = gt * 16 + (lane & 15);
  int k0 = kc * 32 + ((lane >> 4) * 8);
  const float* src = W + (size_t)row * HH + k0;
  f16x8 v;
#pragma unroll
  for (int i = 0; i < 8; ++i) v[i] = (_Float16)src[i];
  *reinterpret_cast<f16x8*>(P + (size_t)id * 8) = v;
}

// ---------------- MFMA recurrent scan, 4-way N-split, r8-proven sync + prefetch ----------
// 64 blocks = 16 seq-groups x 4 N-groups; 512 threads (8 waves). bid remap puts the 4
// exchanging peers (same sg) on the SAME XCD (bids differ by 16 == 0 mod 8).
// Sound protocol (absmax=0 in r7/r8/r9): plain hx stores -> __threadfence -> barrier ->
// release-store own flag; consumers acquire-poll 4 flags in 4 lanes -> barrier -> plain
// hx loads. KEY CHANGE vs r8: next step's weight tiles are prefetched into registers
// BEFORE the fence/spin — weights are constants, so stale-cache fills are correct, and
// registers are immune to the acquire's L2 invalidation. This removes the ~10 us/step
// cold-LLC weight restream that dominated r8.
#define SPB2 16
#define HSTR 520

#define LOADW(buf, g)                                                            \
  {                                                                              \
    const _Float16* _s = packW +                                                 \
        (((size_t)(ng * 24 + (g) * 8 + wid)) * 16) * 512 + (size_t)lane * 8;     \
    _Pragma("unroll")                                                            \
    for (int kc = 0; kc < 16; ++kc)                                              \
      buf[kc] = *reinterpret_cast<const f16x8*>(_s + (size_t)kc * 512);          \
  }

#define MF16(buf, acc)                                                           \
  {                                                                              \
    _Pragma("unroll")                                                            \
    for (int kc = 0; kc < 16; ++kc) {                                            \
      f16x8 _ha = *reinterpret_cast<const f16x8*>(&hs[arow][kc * 32 + agrp * 8]); \
      acc = __builtin_amdgcn_mfma_f32_16x16x32_f16(_ha, buf[kc], acc, 0, 0, 0);  \
    }                                                                            \
  }

__global__ __launch_bounds__(512, 2) void gru_scan_mfma(
    const float* __restrict__ gi,      // [NSEQ][TT][G3]
    const _Float16* __restrict__ packW,
    const float* __restrict__ bhh,     // [G3]
    float* __restrict__ hfin,          // [NSEQ][HH]
    float* __restrict__ yout,          // [NSEQ][TT][HH] or nullptr
    _Float16* __restrict__ hx,         // [2][NSEQ][HH] exchange buffer
    unsigned int* __restrict__ flags)  // [SGRP][NGRP][TT], zeroed pre-launch
{
  __shared__ __align__(16) _Float16 hs[SPB2][HSTR];   // 16.6 KB

  const int tid = threadIdx.x;
  const int lane = tid & 63;
  const int wid = tid >> 6;                   // 0..7
  const int bid = blockIdx.x;
  const int sg = bid & 15;                    // seq group   (peers: bid, +16, +32, +48)
  const int ng = bid >> 4;                    // N group     (same XCD under %8 dispatch)
  const int seq0 = sg * SPB2;

  const int arow = lane & 15;                 // A-frag row (seq)
  const int agrp = lane >> 4;
  const int dcol = lane & 15;                 // D-frag col within tile
  const int mrow = (lane >> 4) * 4;           // D-frag first row (seq)

  const int cg = ng * 128 + wid * 16 + dcol;  // this lane's h column (global)

  const float bhr = bhh[cg];
  const float bhz = bhh[HH + cg];
  const float bhn = bhh[2 * HH + cg];

  float hold[4] = {0.f, 0.f, 0.f, 0.f};

  // zero LDS h (used directly at t=0)
  for (int e = tid; e < SPB2 * HSTR; e += 512)
    hs[e / HSTR][e % HSTR] = (_Float16)0.f;
  __syncthreads();

  // prime the 2-deep weight register pipeline (tiles 0,1 of step 0)
  f16x8 bufA[16], bufB[16];
  LOADW(bufA, 0)
  LOADW(bufB, 1)

  for (int t = 0; t < TT; ++t) {
    // ---- gi loads (cached; independent of exchange, in flight during spin) ----
    float gir[4], giz[4], gin[4];
#pragma unroll
    for (int r = 0; r < 4; ++r) {
      const float* p0 = gi + ((size_t)(seq0 + mrow + r) * TT + t) * G3;
      gir[r] = p0[cg];
      giz[r] = p0[HH + cg];
      gin[r] = p0[2 * HH + cg];
    }

    if (t > 0) {
      // 4 poller lanes, one per producer block of this group (separate flag lines)
      if (tid < NGRP) {
        const unsigned int* fp = &flags[((size_t)sg * NGRP + tid) * TT + (t - 1)];
        while (__hip_atomic_load(fp, __ATOMIC_ACQUIRE, __HIP_MEMORY_SCOPE_AGENT) == 0u) {}
      }
      __syncthreads();
      // copy h(t-1) [16 seqs x 512 fp16] from hx[t&1] into LDS
      {
        const _Float16* src = hx + (size_t)(t & 1) * NSEQ * HH
                              + (size_t)seq0 * HH + (size_t)tid * 16;
        int e0 = tid * 16;
        int row = e0 >> 9;
        int col = e0 & 511;
        *reinterpret_cast<f16x8*>(&hs[row][col])     = *reinterpret_cast<const f16x8*>(src);
        *reinterpret_cast<f16x8*>(&hs[row][col + 8]) = *reinterpret_cast<const f16x8*>(src + 8);
      }
      __syncthreads();
    }

    // ---- 3 gate tiles; bufA/bufB were prefetched BEFORE the fences ----
    f32x4 aR = {0.f,0.f,0.f,0.f}, aZ = {0.f,0.f,0.f,0.f}, aN = {0.f,0.f,0.f,0.f};
    MF16(bufA, aR)
    LOADW(bufA, 2)          // tile n for THIS step (short exposure ~0.3 us)
    MF16(bufB, aZ)
    MF16(bufA, aN)
    LOADW(bufA, 0)          // prefetch NEXT step tile r (fills under fence+spin)
    LOADW(bufB, 1)          // prefetch NEXT step tile z

    // ---- register-local gate epilogue: 4 seqs x 1 col per lane ----
    const int nb = (t + 1) & 1;
#pragma unroll
    for (int r = 0; r < 4; ++r) {
      float hr = aR[r] + bhr;
      float hz = aZ[r] + bhz;
      float hn = aN[r] + bhn;
      float rr = __builtin_amdgcn_rcpf(1.f + __expf(-(gir[r] + hr)));
      float zz = __builtin_amdgcn_rcpf(1.f + __expf(-(giz[r] + hz)));
      float ex = __expf(2.f * (gin[r] + rr * hn));
      float nn = 1.f - 2.f * __builtin_amdgcn_rcpf(ex + 1.f);
      float hnew = nn + zz * (hold[r] - nn);
      hold[r] = hnew;
      hx[(size_t)nb * NSEQ * HH + (size_t)(seq0 + mrow + r) * HH + cg] = (_Float16)hnew;
      if (yout)   // nt store: keep L2 clean (cheap wbl2); y0 lands in LLC for GEMM1
        __builtin_nontemporal_store(hnew, yout + ((size_t)(seq0 + mrow + r) * TT + t) * HH + cg);
    }

    // publish step t (r8-proven): all threads fence, barrier, one release store
    __threadfence();
    __syncthreads();
    if (tid == 0)
      __hip_atomic_store(&flags[((size_t)sg * NGRP + ng) * TT + t], 1u,
                         __ATOMIC_RELEASE, __HIP_MEMORY_SCOPE_AGENT);
  }

#pragma unroll
  for (int r = 0; r < 4; ++r)
    hfin[(size_t)(seq0 + mrow + r) * HH + cg] = hold[r];
}

// ---------------- fallback fp32 scan (row-streaming) ----------------
#define QS 4
#define SCTH 512
__global__ __launch_bounds__(SCTH) void gru_scan2f(
    const float* __restrict__ gi, const float* __restrict__ W,
    const float* __restrict__ bhh, float* __restrict__ hfin,
    float* __restrict__ yout)
{
  __shared__ __align__(16) float hsl[HH][QS];
  const int col = threadIdx.x;
  const int seq0 = blockIdx.x * QS;
  const float bh0 = bhh[col];
  const float bh1 = bhh[HH + col];
  const float bh2 = bhh[2 * HH + col];
  const float* w0p = W + (size_t)col * HH;
  const float* w1p = W + (size_t)(HH + col) * HH;
  const float* w2p = W + (size_t)(2 * HH + col) * HH;

  *reinterpret_cast<float4*>(&hsl[col][0]) = make_float4(0.f, 0.f, 0.f, 0.f);
  __syncthreads();

  for (int t = 0; t < TT; ++t) {
    float acc0[QS], acc1[QS], acc2[QS];
#pragma unroll
    for (int s = 0; s < QS; ++s) { acc0[s] = bh0; acc1[s] = bh1; acc2[s] = bh2; }
    float4 ho = *reinterpret_cast<const float4*>(&hsl[col][0]);
    float hold[QS] = {ho.x, ho.y, ho.z, ho.w};
#pragma unroll 2
    for (int k0 = 0; k0 < HH; k0 += 4) {
      float w[3][4];
      float4 a = *reinterpret_cast<const float4*>(&w0p[k0]);
      w[0][0] = a.x; w[0][1] = a.y; w[0][2] = a.z; w[0][3] = a.w;
      float4 b = *reinterpret_cast<const float4*>(&w1p[k0]);
      w[1][0] = b.x; w[1][1] = b.y; w[1][2] = b.z; w[1][3] = b.w;
      float4 c = *reinterpret_cast<const float4*>(&w2p[k0]);
      w[2][0] = c.x; w[2][1] = c.y; w[2][2] = c.z; w[2][3] = c.w;
#pragma unroll
      for (int kk = 0; kk < 4; ++kk) {
        float4 h4 = *reinterpret_cast<const float4*>(&hsl[k0 + kk][0]);
        float hq[4] = {h4.x, h4.y, h4.z, h4.w};
#pragma unroll
        for (int s = 0; s < QS; ++s) {
          acc0[s] = fmaf(hq[s], w[0][kk], acc0[s]);
          acc1[s] = fmaf(hq[s], w[1][kk], acc1[s]);
          acc2[s] = fmaf(hq[s], w[2][kk], acc2[s]);
        }
      }
    }
    __syncthreads();
    float hnew[QS];
#pragma unroll
    for (int s = 0; s < QS; ++s) {
      size_t grow = ((size_t)(seq0 + s) * TT + t) * G3;
      float ir = gi[grow + col];
      float iz = gi[grow + HH + col];
      float inn = gi[grow + 2 * HH + col];
      float r = 1.f / (1.f + expf(-(ir + acc0[s])));
      float z = 1.f / (1.f + expf(-(iz + acc1[s])));
      float nn = tanhf(inn + r * acc2[s]);
      hnew[s] = (1.f - z) * nn + z * hold[s];
      if (yout) yout[((size_t)(seq0 + s) * TT + t) * HH + col] = hnew[s];
    }
    *reinterpret_cast<float4*>(&hsl[col][0]) =
        make_float4(hnew[0], hnew[1], hnew[2], hnew[3]);
    __syncthreads();
  }
#pragma unroll
  for (int s = 0; s < QS; ++s)
    hfin[(size_t)(seq0 + s) * HH + col] = hsl[col][s];
}

// ---------------- final FC + channel mean ----------------
__global__ __launch_bounds__(256) void fc_mean(
    const float* __restrict__ hfin, const float* __restrict__ fcW,
    const float* __restrict__ fcb, float* __restrict__ out)
{
  __shared__ float red[256];
  const int b = blockIdx.x;
  const int tid = threadIdx.x;
  float sum = 0.f;
  for (int e = tid; e < CC * HH; e += 256) {
    int c = e >> 9;
    int k = e & (HH - 1);
    sum += hfin[(size_t)(b * CC + c) * HH + k] * fcW[k];
  }
  red[tid] = sum;
  __syncthreads();
  for (int w = 128; w > 0; w >>= 1) {
    if (tid < w) red[tid] += red[tid + w];
    __syncthreads();
  }
  if (tid == 0) out[b] = red[0] * (1.f / CC) + fcb[0];
}

extern "C" void kernel_launch(void* const* d_in, const int* in_sizes, int n_in,
                              void* d_out, int out_size, void* d_ws, size_t ws_size,
                              hipStream_t stream)
{
  const float* x    = (const float*)d_in[0];
  const float* Wih0 = (const float*)d_in[1];
  const float* Whh0 = (const float*)d_in[2];
  const float* bih0 = (const float*)d_in[3];
  const float* bhh0 = (const float*)d_in[4];
  const float* Wih1 = (const float*)d_in[5];
  const float* Whh1 = (const float*)d_in[6];
  const float* bih1 = (const float*)d_in[7];
  const float* bhh1 = (const float*)d_in[8];
  const float* fcW  = (const float*)d_in[9];
  const float* fcb  = (const float*)d_in[10];
  float* out = (float*)d_out;

  // ws layout:
  //   gi   [MROWS][G3] fp32   100,663,296 @ 0
  //   y0   [MROWS][HH] fp32    33,554,432 @ 100,663,296
  //   hfin [NSEQ][HH]  fp32       524,288 @ 134,217,728
  //   pack fp16               1,572,864 @ 134,742,016
  //   hx   [2][NSEQ][HH] fp16   524,288 @ 136,314,880
  //   flags [SGRP][NGRP][TT] u32 16,384 @ 136,839,168   (end 136,855,552)
  char* ws = (char*)d_ws;
  float* gibuf = (float*)ws;
  float* y0    = (float*)(ws + 100663296ull);
  float* hfin  = (float*)(ws + 134217728ull);
  _Float16* packb = (_Float16*)(ws + 134742016ull);
  _Float16* hx    = (_Float16*)(ws + 136314880ull);
  unsigned int* flags = (unsigned int*)(ws + 136839168ull);
  const bool mfma_ok = (ws_size >= 136855552ull);

  // layer 0 input GEMM
  gemm_bias<<<dim3(G3 / TNg, MROWS / TMg), 256, 0, stream>>>(x, Wih0, bih0, gibuf, MROWS, G3, FF);

  if (mfma_ok) {
    pack_whh<<<dim3(384), 256, 0, stream>>>(Whh0, packb);
    hipMemsetAsync(flags, 0, SGRP * NGRP * TT * sizeof(unsigned int), stream);
    gru_scan_mfma<<<dim3(SGRP * NGRP), 512, 0, stream>>>(gibuf, packb, bhh0, hfin, y0, hx, flags);
  } else {
    gru_scan2f<<<dim3(NSEQ / QS), SCTH, 0, stream>>>(gibuf, Whh0, bhh0, hfin, y0);
  }

  // layer 1 input GEMM (gi reused)
  gemm_bias<<<dim3(G3 / TNg, MROWS / TMg), 256, 0, stream>>>(y0, Wih1, bih1, gibuf, MROWS, G3, HH);

  if (mfma_ok) {
    pack_whh<<<dim3(384), 256, 0, stream>>>(Whh1, packb);
    hipMemsetAsync(flags, 0, SGRP * NGRP * TT * sizeof(unsigned int), stream);
    gru_scan_mfma<<<dim3(SGRP * NGRP), 512, 0, stream>>>(gibuf, packb, bhh1, hfin, nullptr, hx, flags);
  } else {
    gru_scan2f<<<dim3(NSEQ / QS), SCTH, 0, stream>>>(gibuf, Whh1, bhh1, hfin, nullptr);
  }

  fc_mean<<<dim3(BB), 256, 0, stream>>>(hfin, fcW, fcb, out);
}